// Round 1
// baseline (122.707 us; speedup 1.0000x reference)
//
#include <hip/hip_runtime.h>
#include <math.h>

// ---------------------------------------------------------------------------
// Stage 1: quanvolution features. One thread per (batch, patch).
// Exact 4-qubit real state-vector sim in 16 registers.
// Index convention: i = b0*8 + b1*4 + b2*2 + b3, wire w <-> bit (3-w).
// ---------------------------------------------------------------------------

__device__ __forceinline__ void ry_gate(float a[16], int bitpos, float c, float s) {
    const int mask = 1 << bitpos;
#pragma unroll
    for (int i = 0; i < 16; ++i) {
        if (!(i & mask)) {
            const int j = i | mask;
            const float a0 = a[i], a1 = a[j];
            a[i] = c * a0 - s * a1;
            a[j] = s * a0 + c * a1;
        }
    }
}

__device__ __forceinline__ void cnot_gate(float a[16], int cbit, int tbit) {
    const int cmask = 1 << cbit, tmask = 1 << tbit;
#pragma unroll
    for (int i = 0; i < 16; ++i) {
        if ((i & cmask) && !(i & tmask)) {
            const int j = i | tmask;
            const float tmp = a[i];
            a[i] = a[j];
            a[j] = tmp;
        }
    }
}

__global__ __launch_bounds__(256) void quanv_kernel(
        const float* __restrict__ x, const float* __restrict__ var_angles,
        float* __restrict__ feats, int total) {
    const int idx = blockIdx.x * 256 + threadIdx.x;
    if (idx >= total) return;
    const int b = idx / 196;
    const int p = idx - b * 196;
    const int pr = p / 14;
    const int pc = p - pr * 14;

    const float* img = x + (size_t)b * 784;
    const float2 top = *(const float2*)(img + (2 * pr) * 28 + 2 * pc);
    const float2 bot = *(const float2*)(img + (2 * pr + 1) * 28 + 2 * pc);
    const float theta[4] = {top.x, top.y, bot.x, bot.y};

    // Encoder: RY(pixel_w) on wire w applied to |0000> -> product state.
    float c[4], s[4];
#pragma unroll
    for (int w = 0; w < 4; ++w) sincosf(0.5f * theta[w], &s[w], &c[w]);

    float a[16];
#pragma unroll
    for (int i = 0; i < 16; ++i) {
        float v = (i & 8) ? s[0] : c[0];
        v *= (i & 4) ? s[1] : c[1];
        v *= (i & 2) ? s[2] : c[2];
        v *= (i & 1) ? s[3] : c[3];
        a[i] = v;
    }

    // Variational layers: RY(var[d][w]) each wire, then CNOT ring 0->1->2->3->0.
#pragma unroll
    for (int d = 0; d < 2; ++d) {
#pragma unroll
        for (int w = 0; w < 4; ++w) {
            float vs, vc;
            sincosf(0.5f * var_angles[d * 4 + w], &vs, &vc);
            ry_gate(a, 3 - w, vc, vs);
        }
        cnot_gate(a, 3 - 0, 3 - 1);
        cnot_gate(a, 3 - 1, 3 - 2);
        cnot_gate(a, 3 - 2, 3 - 3);
        cnot_gate(a, 3 - 3, 3 - 0);
    }

    // <Z_w> = sum_{bit_w=0} |a|^2 - sum_{bit_w=1} |a|^2
    float z0 = 0.f, z1 = 0.f, z2 = 0.f, z3 = 0.f;
#pragma unroll
    for (int i = 0; i < 16; ++i) {
        const float pr2 = a[i] * a[i];
        z0 += (i & 8) ? -pr2 : pr2;
        z1 += (i & 4) ? -pr2 : pr2;
        z2 += (i & 2) ? -pr2 : pr2;
        z3 += (i & 1) ? -pr2 : pr2;
    }
    *(float4*)(feats + (size_t)idx * 4) = make_float4(z0, z1, z2, z3);
}

// ---------------------------------------------------------------------------
// Stage 2: H = relu(feats @ W1^T + b1).  [4096,784] x [256,784]^T -> [4096,256]
// 64x64 tile / block, 4x4 micro-tile / thread, BK=16, register prefetch.
// LDS rows padded to 68 floats: keeps 16B alignment for ds_read_b128 and
// reduces staging-write bank conflicts to free 2-way.
// ---------------------------------------------------------------------------

__global__ __launch_bounds__(256) void gemm1_relu_kernel(
        const float* __restrict__ A, const float* __restrict__ W1,
        const float* __restrict__ b1, float* __restrict__ H) {
    __shared__ float As[16][68];
    __shared__ float Bs[16][68];

    const int t = threadIdx.x;
    const int row0 = blockIdx.x * 64;
    const int col0 = blockIdx.y * 64;
    const int tx = t & 15;   // micro col group
    const int ty = t >> 4;   // micro row group
    const int lr = t >> 2;   // staging: row/col 0..63
    const int lc = t & 3;    // staging: k chunk 0..3 (x4 floats)

    const float* Aptr = A + (size_t)(row0 + lr) * 784 + lc * 4;
    const float* Bptr = W1 + (size_t)(col0 + lr) * 784 + lc * 4;

    float acc[4][4] = {};

    float4 av = *(const float4*)(Aptr);
    float4 bv = *(const float4*)(Bptr);

    for (int k0 = 0; k0 < 784; k0 += 16) {
        __syncthreads();
        As[lc * 4 + 0][lr] = av.x;
        As[lc * 4 + 1][lr] = av.y;
        As[lc * 4 + 2][lr] = av.z;
        As[lc * 4 + 3][lr] = av.w;
        Bs[lc * 4 + 0][lr] = bv.x;
        Bs[lc * 4 + 1][lr] = bv.y;
        Bs[lc * 4 + 2][lr] = bv.z;
        Bs[lc * 4 + 3][lr] = bv.w;
        __syncthreads();

        if (k0 + 16 < 784) {  // prefetch next tile under compute
            av = *(const float4*)(Aptr + k0 + 16);
            bv = *(const float4*)(Bptr + k0 + 16);
        }

#pragma unroll
        for (int k = 0; k < 16; ++k) {
            const float4 a4 = *(const float4*)&As[k][ty * 4];
            const float4 b4 = *(const float4*)&Bs[k][tx * 4];
            acc[0][0] += a4.x * b4.x; acc[0][1] += a4.x * b4.y;
            acc[0][2] += a4.x * b4.z; acc[0][3] += a4.x * b4.w;
            acc[1][0] += a4.y * b4.x; acc[1][1] += a4.y * b4.y;
            acc[1][2] += a4.y * b4.z; acc[1][3] += a4.y * b4.w;
            acc[2][0] += a4.z * b4.x; acc[2][1] += a4.z * b4.y;
            acc[2][2] += a4.z * b4.z; acc[2][3] += a4.z * b4.w;
            acc[3][0] += a4.w * b4.x; acc[3][1] += a4.w * b4.y;
            acc[3][2] += a4.w * b4.z; acc[3][3] += a4.w * b4.w;
        }
    }

    const int cc = col0 + tx * 4;
    const float4 bias = *(const float4*)(b1 + cc);
#pragma unroll
    for (int i = 0; i < 4; ++i) {
        const int m = row0 + ty * 4 + i;
        float4 o;
        o.x = fmaxf(acc[i][0] + bias.x, 0.f);
        o.y = fmaxf(acc[i][1] + bias.y, 0.f);
        o.z = fmaxf(acc[i][2] + bias.z, 0.f);
        o.w = fmaxf(acc[i][3] + bias.w, 0.f);
        *(float4*)(H + (size_t)m * 256 + cc) = o;
    }
}

// ---------------------------------------------------------------------------
// Stage 3: logits = H @ W2^T + b2; out = log_softmax(logits).
// One wave (64 lanes) per batch row; butterfly shfl reductions over 256.
// ---------------------------------------------------------------------------

__global__ __launch_bounds__(256) void mlp2_lsm_kernel(
        const float* __restrict__ H, const float* __restrict__ W2,
        const float* __restrict__ b2, float* __restrict__ out) {
    const int lane = threadIdx.x & 63;
    const int wv = threadIdx.x >> 6;
    const int b = blockIdx.x * 4 + wv;

    const float4 h = *(const float4*)(H + (size_t)b * 256 + lane * 4);

    float logits[10];
#pragma unroll
    for (int j = 0; j < 10; ++j) {
        const float4 w = *(const float4*)(W2 + (size_t)j * 256 + lane * 4);
        float d = h.x * w.x + h.y * w.y + h.z * w.z + h.w * w.w;
#pragma unroll
        for (int off = 32; off > 0; off >>= 1) d += __shfl_xor(d, off, 64);
        logits[j] = d + b2[j];
    }

    float m = logits[0];
#pragma unroll
    for (int j = 1; j < 10; ++j) m = fmaxf(m, logits[j]);
    float se = 0.f;
#pragma unroll
    for (int j = 0; j < 10; ++j) se += expf(logits[j] - m);
    const float lse = m + logf(se);

    if (lane == 0) {
#pragma unroll
        for (int j = 0; j < 10; ++j) out[(size_t)b * 10 + j] = logits[j] - lse;
    }
}

// ---------------------------------------------------------------------------

extern "C" void kernel_launch(void* const* d_in, const int* in_sizes, int n_in,
                              void* d_out, int out_size, void* d_ws, size_t ws_size,
                              hipStream_t stream) {
    const float* x   = (const float*)d_in[0];  // [B,1,28,28]
    const float* var = (const float*)d_in[1];  // [2,4]
    const float* W1  = (const float*)d_in[2];  // [256,784]
    const float* b1  = (const float*)d_in[3];  // [256]
    const float* W2  = (const float*)d_in[4];  // [10,256]
    const float* b2  = (const float*)d_in[5];  // [10]
    float* out = (float*)d_out;                // [B,10]

    const int B = in_sizes[0] / 784;           // 4096

    float* feats = (float*)d_ws;               // [B,784] fp32
    float* H = feats + (size_t)B * 784;        // [B,256] fp32

    const int total = B * 196;
    quanv_kernel<<<(total + 255) / 256, 256, 0, stream>>>(x, var, feats, total);
    gemm1_relu_kernel<<<dim3(B / 64, 256 / 64), 256, 0, stream>>>(feats, W1, b1, H);
    mlp2_lsm_kernel<<<B / 4, 256, 0, stream>>>(H, W2, b2, out);
}

// Round 2
// 109.645 us; speedup vs baseline: 1.1191x; 1.1191x over previous
//
#include <hip/hip_runtime.h>
#include <math.h>

typedef short bf16x8 __attribute__((ext_vector_type(8)));
typedef float f32x4 __attribute__((ext_vector_type(4)));

// ---- fp32 <-> bf16 split helpers (RNE) ------------------------------------
__device__ __forceinline__ unsigned short f2bf(float f) {
    unsigned int u = __float_as_uint(f);
    u = (u + 0x7FFFu + ((u >> 16) & 1u)) >> 16;
    return (unsigned short)u;
}
__device__ __forceinline__ float bf2f(unsigned short h) {
    return __uint_as_float(((unsigned int)h) << 16);
}

// ---------------------------------------------------------------------------
// Stage 1: quanvolution features. One thread per (batch, patch).
// Exact 4-qubit real state-vector sim in 16 registers. Output: split-bf16
// feats (hi + lo) padded to K=800 (cols 784..799 zeroed for MFMA K-tiling).
// ---------------------------------------------------------------------------

__device__ __forceinline__ void ry_gate(float a[16], int bitpos, float c, float s) {
    const int mask = 1 << bitpos;
#pragma unroll
    for (int i = 0; i < 16; ++i) {
        if (!(i & mask)) {
            const int j = i | mask;
            const float a0 = a[i], a1 = a[j];
            a[i] = c * a0 - s * a1;
            a[j] = s * a0 + c * a1;
        }
    }
}

__device__ __forceinline__ void cnot_gate(float a[16], int cbit, int tbit) {
    const int cmask = 1 << cbit, tmask = 1 << tbit;
#pragma unroll
    for (int i = 0; i < 16; ++i) {
        if ((i & cmask) && !(i & tmask)) {
            const int j = i | tmask;
            const float tmp = a[i];
            a[i] = a[j];
            a[j] = tmp;
        }
    }
}

__global__ __launch_bounds__(256) void quanv_kernel(
        const float* __restrict__ x, const float* __restrict__ var_angles,
        unsigned short* __restrict__ fhi, unsigned short* __restrict__ flo,
        int total) {
    const int idx = blockIdx.x * 256 + threadIdx.x;
    if (idx >= total) return;
    const int b = idx / 196;
    const int p = idx - b * 196;
    const int pr = p / 14;
    const int pc = p - pr * 14;

    const float* img = x + (size_t)b * 784;
    const float2 top = *(const float2*)(img + (2 * pr) * 28 + 2 * pc);
    const float2 bot = *(const float2*)(img + (2 * pr + 1) * 28 + 2 * pc);
    const float theta[4] = {top.x, top.y, bot.x, bot.y};

    float c[4], s[4];
#pragma unroll
    for (int w = 0; w < 4; ++w) sincosf(0.5f * theta[w], &s[w], &c[w]);

    float a[16];
#pragma unroll
    for (int i = 0; i < 16; ++i) {
        float v = (i & 8) ? s[0] : c[0];
        v *= (i & 4) ? s[1] : c[1];
        v *= (i & 2) ? s[2] : c[2];
        v *= (i & 1) ? s[3] : c[3];
        a[i] = v;
    }

#pragma unroll
    for (int d = 0; d < 2; ++d) {
#pragma unroll
        for (int w = 0; w < 4; ++w) {
            float vs, vc;
            sincosf(0.5f * var_angles[d * 4 + w], &vs, &vc);
            ry_gate(a, 3 - w, vc, vs);
        }
        cnot_gate(a, 3, 2);
        cnot_gate(a, 2, 1);
        cnot_gate(a, 1, 0);
        cnot_gate(a, 0, 3);
    }

    float z[4] = {0.f, 0.f, 0.f, 0.f};
#pragma unroll
    for (int i = 0; i < 16; ++i) {
        const float pr2 = a[i] * a[i];
        z[0] += (i & 8) ? -pr2 : pr2;
        z[1] += (i & 4) ? -pr2 : pr2;
        z[2] += (i & 2) ? -pr2 : pr2;
        z[3] += (i & 1) ? -pr2 : pr2;
    }

    ushort4 hv, lv;
    unsigned short* hp = (unsigned short*)&hv;
    unsigned short* lp = (unsigned short*)&lv;
#pragma unroll
    for (int w = 0; w < 4; ++w) {
        const unsigned short h = f2bf(z[w]);
        hp[w] = h;
        lp[w] = f2bf(z[w] - bf2f(h));
    }
    const size_t off = (size_t)b * 800 + p * 4;
    *(ushort4*)(fhi + off) = hv;
    *(ushort4*)(flo + off) = lv;

    if (p < 4) {  // zero K-padding cols 784..799 (ws is poisoned 0xAA)
        const ushort4 zz = {0, 0, 0, 0};
        const size_t poff = (size_t)b * 800 + 784 + p * 4;
        *(ushort4*)(fhi + poff) = zz;
        *(ushort4*)(flo + poff) = zz;
    }
}

// ---------------------------------------------------------------------------
// W1 [256,784] fp32 -> split bf16 hi/lo, K-padded to [256,800].
// ---------------------------------------------------------------------------
__global__ __launch_bounds__(256) void w1cvt_kernel(
        const float* __restrict__ W1,
        unsigned short* __restrict__ hi, unsigned short* __restrict__ lo) {
    const int id = blockIdx.x * 256 + threadIdx.x;  // 0 .. 256*800-1
    const int r = id / 800;
    const int c = id - r * 800;
    const float v = (c < 784) ? W1[r * 784 + c] : 0.f;
    const unsigned short h = f2bf(v);
    hi[id] = h;
    lo[id] = f2bf(v - bf2f(h));
}

// ---------------------------------------------------------------------------
// Stage 2: H = relu(feats @ W1^T + b1) via split-bf16 MFMA.
// C = Ah*Bh + Ah*Bl + Al*Bh (al*bl dropped, ~2^-18 relative).
// 64x64 tile / block (256 thr = 4 waves), BK=32, mfma_f32_16x16x32_bf16.
// Wave wv owns rows [wv*16, wv*16+16) x all 64 cols (4 n-tiles).
// LDS rows padded to 40 ushorts (80 B: 16B-aligned, breaks pow2 bank stride).
// A-frag: A[m=lane&15][k=quad*8+j]; B^T-frag same pattern; C/D: col=lane&15,
// row=quad*4+reg (m89-verified layouts).
// ---------------------------------------------------------------------------
__global__ __launch_bounds__(256) void gemm1_mfma_kernel(
        const unsigned short* __restrict__ Ahi_g, const unsigned short* __restrict__ Alo_g,
        const unsigned short* __restrict__ Bhi_g, const unsigned short* __restrict__ Blo_g,
        const float* __restrict__ b1, float* __restrict__ H) {
    __shared__ unsigned short Ahi[64][40];
    __shared__ unsigned short Alo[64][40];
    __shared__ unsigned short Bhi[64][40];
    __shared__ unsigned short Blo[64][40];

    const int t = threadIdx.x;
    const int row0 = blockIdx.x * 64;
    const int col0 = blockIdx.y * 64;
    const int lane = t & 63;
    const int wv = t >> 6;
    const int q = lane >> 4;
    const int lm = lane & 15;

    const int sr = t >> 2;        // staging row 0..63
    const int sk = (t & 3) * 8;   // staging k-chunk (8 bf16 = 16 B)

    const unsigned short* pAhi = Ahi_g + (size_t)(row0 + sr) * 800 + sk;
    const unsigned short* pAlo = Alo_g + (size_t)(row0 + sr) * 800 + sk;
    const unsigned short* pBhi = Bhi_g + (size_t)(col0 + sr) * 800 + sk;
    const unsigned short* pBlo = Blo_g + (size_t)(col0 + sr) * 800 + sk;

    f32x4 acc[4];
#pragma unroll
    for (int i = 0; i < 4; ++i) acc[i] = (f32x4)(0.f);

    float4 vah = *(const float4*)pAhi;
    float4 val = *(const float4*)pAlo;
    float4 vbh = *(const float4*)pBhi;
    float4 vbl = *(const float4*)pBlo;

    for (int k0 = 0; k0 < 800; k0 += 32) {
        __syncthreads();
        *(float4*)&Ahi[sr][sk] = vah;
        *(float4*)&Alo[sr][sk] = val;
        *(float4*)&Bhi[sr][sk] = vbh;
        *(float4*)&Blo[sr][sk] = vbl;
        __syncthreads();

        if (k0 + 32 < 800) {  // prefetch next K-tile under compute
            vah = *(const float4*)(pAhi + k0 + 32);
            val = *(const float4*)(pAlo + k0 + 32);
            vbh = *(const float4*)(pBhi + k0 + 32);
            vbl = *(const float4*)(pBlo + k0 + 32);
        }

        const bf16x8 ah = *(const bf16x8*)&Ahi[wv * 16 + lm][q * 8];
        const bf16x8 al = *(const bf16x8*)&Alo[wv * 16 + lm][q * 8];
#pragma unroll
        for (int nt = 0; nt < 4; ++nt) {
            const bf16x8 bh = *(const bf16x8*)&Bhi[nt * 16 + lm][q * 8];
            const bf16x8 bl = *(const bf16x8*)&Blo[nt * 16 + lm][q * 8];
            acc[nt] = __builtin_amdgcn_mfma_f32_16x16x32_bf16(ah, bh, acc[nt], 0, 0, 0);
            acc[nt] = __builtin_amdgcn_mfma_f32_16x16x32_bf16(ah, bl, acc[nt], 0, 0, 0);
            acc[nt] = __builtin_amdgcn_mfma_f32_16x16x32_bf16(al, bh, acc[nt], 0, 0, 0);
        }
    }

#pragma unroll
    for (int nt = 0; nt < 4; ++nt) {
        const int n = col0 + nt * 16 + lm;
        const float bias = b1[n];
#pragma unroll
        for (int i = 0; i < 4; ++i) {
            const int m = row0 + wv * 16 + q * 4 + i;
            H[(size_t)m * 256 + n] = fmaxf(acc[nt][i] + bias, 0.f);
        }
    }
}

// ---------------------------------------------------------------------------
// Stage 3: logits = H @ W2^T + b2; out = log_softmax(logits).
// One wave per batch row; butterfly shfl reductions.
// ---------------------------------------------------------------------------
__global__ __launch_bounds__(256) void mlp2_lsm_kernel(
        const float* __restrict__ H, const float* __restrict__ W2,
        const float* __restrict__ b2, float* __restrict__ out) {
    const int lane = threadIdx.x & 63;
    const int wv = threadIdx.x >> 6;
    const int b = blockIdx.x * 4 + wv;

    const float4 h = *(const float4*)(H + (size_t)b * 256 + lane * 4);

    float logits[10];
#pragma unroll
    for (int j = 0; j < 10; ++j) {
        const float4 w = *(const float4*)(W2 + (size_t)j * 256 + lane * 4);
        float d = h.x * w.x + h.y * w.y + h.z * w.z + h.w * w.w;
#pragma unroll
        for (int off = 32; off > 0; off >>= 1) d += __shfl_xor(d, off, 64);
        logits[j] = d + b2[j];
    }

    float m = logits[0];
#pragma unroll
    for (int j = 1; j < 10; ++j) m = fmaxf(m, logits[j]);
    float se = 0.f;
#pragma unroll
    for (int j = 0; j < 10; ++j) se += expf(logits[j] - m);
    const float lse = m + logf(se);

    if (lane == 0) {
#pragma unroll
        for (int j = 0; j < 10; ++j) out[(size_t)b * 10 + j] = logits[j] - lse;
    }
}

// ---------------------------------------------------------------------------

extern "C" void kernel_launch(void* const* d_in, const int* in_sizes, int n_in,
                              void* d_out, int out_size, void* d_ws, size_t ws_size,
                              hipStream_t stream) {
    const float* x   = (const float*)d_in[0];  // [B,1,28,28]
    const float* var = (const float*)d_in[1];  // [2,4]
    const float* W1  = (const float*)d_in[2];  // [256,784]
    const float* b1  = (const float*)d_in[3];  // [256]
    const float* W2  = (const float*)d_in[4];  // [10,256]
    const float* b2  = (const float*)d_in[5];  // [10]
    float* out = (float*)d_out;                // [B,10]

    const int B = in_sizes[0] / 784;           // 4096
    const int KP = 800;                        // 784 padded to 25*32

    char* ws = (char*)d_ws;
    unsigned short* fhi = (unsigned short*)ws;                    // [B,800] bf16
    unsigned short* flo = fhi + (size_t)B * KP;                   // [B,800] bf16
    unsigned short* w1hi = flo + (size_t)B * KP;                  // [256,800]
    unsigned short* w1lo = w1hi + (size_t)256 * KP;               // [256,800]
    float* H = (float*)(w1lo + (size_t)256 * KP);                 // [B,256] fp32

    const int total = B * 196;
    quanv_kernel<<<(total + 255) / 256, 256, 0, stream>>>(x, var, fhi, flo, total);
    w1cvt_kernel<<<(256 * KP) / 256, 256, 0, stream>>>(W1, w1hi, w1lo);
    gemm1_mfma_kernel<<<dim3(B / 64, 256 / 64), 256, 0, stream>>>(
        fhi, flo, w1hi, w1lo, b1, H);
    mlp2_lsm_kernel<<<B / 4, 256, 0, stream>>>(H, W2, b2, out);
}

// Round 3
// 97.791 us; speedup vs baseline: 1.2548x; 1.1212x over previous
//
#include <hip/hip_runtime.h>
#include <math.h>

typedef short bf16x8 __attribute__((ext_vector_type(8)));
typedef float f32x4 __attribute__((ext_vector_type(4)));

// ---- fp32 -> bf16 (RNE) ---------------------------------------------------
__device__ __forceinline__ unsigned short f2bf(float f) {
    unsigned int u = __float_as_uint(f);
    u = (u + 0x7FFFu + ((u >> 16) & 1u)) >> 16;
    return (unsigned short)u;
}

// ---------------------------------------------------------------------------
// Fused prep + quanv kernel.
//  blocks [0, 800):      W1 [256,784] fp32 -> bf16, K-padded to [256,800]
//  blocks [800, 800+Q):  one thread per (batch, patch) 4-qubit statevector sim
// All trig via hardware v_sin/v_cos (__sinf/__cosf): args are <= ~4 rad,
// abs err ~2e-6 -- far below the 5.6e-2 output threshold.
// ---------------------------------------------------------------------------

__device__ __forceinline__ void ry_gate(float a[16], int bitpos, float c, float s) {
    const int mask = 1 << bitpos;
#pragma unroll
    for (int i = 0; i < 16; ++i) {
        if (!(i & mask)) {
            const int j = i | mask;
            const float a0 = a[i], a1 = a[j];
            a[i] = c * a0 - s * a1;
            a[j] = s * a0 + c * a1;
        }
    }
}

__device__ __forceinline__ void cnot_gate(float a[16], int cbit, int tbit) {
    const int cmask = 1 << cbit, tmask = 1 << tbit;
#pragma unroll
    for (int i = 0; i < 16; ++i) {
        if ((i & cmask) && !(i & tmask)) {
            const int j = i | tmask;
            const float tmp = a[i];
            a[i] = a[j];
            a[j] = tmp;
        }
    }
}

__global__ __launch_bounds__(256) void prep_quanv_kernel(
        const float* __restrict__ x, const float* __restrict__ var_angles,
        const float* __restrict__ W1,
        unsigned short* __restrict__ fhi, unsigned short* __restrict__ w1hi,
        int quanv_total) {
    const int blk = blockIdx.x;
    if (blk < 800) {  // ---- W1 convert (wave-uniform branch) ----
        const int id = blk * 256 + threadIdx.x;  // 0 .. 204799
        const int r = id / 800;
        const int c = id - r * 800;
        const float v = (c < 784) ? W1[r * 784 + c] : 0.f;
        w1hi[id] = f2bf(v);
        return;
    }

    const int idx = (blk - 800) * 256 + threadIdx.x;
    if (idx >= quanv_total) return;
    const int b = idx / 196;
    const int p = idx - b * 196;
    const int pr = p / 14;
    const int pc = p - pr * 14;

    const float* img = x + (size_t)b * 784;
    const float2 top = *(const float2*)(img + (2 * pr) * 28 + 2 * pc);
    const float2 bot = *(const float2*)(img + (2 * pr + 1) * 28 + 2 * pc);
    const float theta[4] = {top.x, top.y, bot.x, bot.y};

    // Encoder: RY(pixel_w) on wire w applied to |0000> -> product state.
    float c[4], s[4];
#pragma unroll
    for (int w = 0; w < 4; ++w) {
        const float h = 0.5f * theta[w];
        s[w] = __sinf(h);
        c[w] = __cosf(h);
    }

    float a[16];
#pragma unroll
    for (int i = 0; i < 16; ++i) {
        float v = (i & 8) ? s[0] : c[0];
        v *= (i & 4) ? s[1] : c[1];
        v *= (i & 2) ? s[2] : c[2];
        v *= (i & 1) ? s[3] : c[3];
        a[i] = v;
    }

    // Variational layers: RY each wire, then CNOT ring 0->1->2->3->0.
#pragma unroll
    for (int d = 0; d < 2; ++d) {
#pragma unroll
        for (int w = 0; w < 4; ++w) {
            const float h = 0.5f * var_angles[d * 4 + w];
            ry_gate(a, 3 - w, __cosf(h), __sinf(h));
        }
        cnot_gate(a, 3, 2);
        cnot_gate(a, 2, 1);
        cnot_gate(a, 1, 0);
        cnot_gate(a, 0, 3);
    }

    // <Z_w> = P(bit_w=0) - P(bit_w=1)
    float z[4] = {0.f, 0.f, 0.f, 0.f};
#pragma unroll
    for (int i = 0; i < 16; ++i) {
        const float pr2 = a[i] * a[i];
        z[0] += (i & 8) ? -pr2 : pr2;
        z[1] += (i & 4) ? -pr2 : pr2;
        z[2] += (i & 2) ? -pr2 : pr2;
        z[3] += (i & 1) ? -pr2 : pr2;
    }

    ushort4 hv;
    unsigned short* hp = (unsigned short*)&hv;
#pragma unroll
    for (int w = 0; w < 4; ++w) hp[w] = f2bf(z[w]);
    *(ushort4*)(fhi + (size_t)b * 800 + p * 4) = hv;

    if (p < 4) {  // zero K-padding cols 784..799 (ws is poisoned 0xAA)
        const ushort4 zz = {0, 0, 0, 0};
        *(ushort4*)(fhi + (size_t)b * 800 + 784 + p * 4) = zz;
    }
}

// ---------------------------------------------------------------------------
// Stage 2: H = relu(feats @ W1^T + b1), single-bf16 MFMA.
// 32x64 tile / block (256 thr = 4 waves) -> grid (128,4) = 512 blocks
// = 2 blocks/CU so waves interleave across the K-loop barriers.
// Wave wv: rows (wv&1)*16..+16, cols (wv>>1)*32..+32 (2 n-tiles).
// LDS rows padded to 40 ushorts (80 B: 16B-aligned, odd-multiple-of-16 bank
// stride -> conflict-free b128 reads).
// A-frag: A[m=lane&15][k=quad*8+j]; C/D: col=lane&15, row=quad*4+reg.
// ---------------------------------------------------------------------------
__global__ __launch_bounds__(256) void gemm1_mfma_kernel(
        const unsigned short* __restrict__ A_g, const unsigned short* __restrict__ B_g,
        const float* __restrict__ b1, float* __restrict__ H) {
    __shared__ unsigned short As[32][40];
    __shared__ unsigned short Bs[64][40];

    const int t = threadIdx.x;
    const int row0 = blockIdx.x * 32;
    const int col0 = blockIdx.y * 64;
    const int lane = t & 63;
    const int wv = t >> 6;
    const int q = lane >> 4;
    const int lm = lane & 15;
    const int mh = wv & 1;        // m-half within 32 rows
    const int np = wv >> 1;       // n-pair (32 cols)

    const int sr = t >> 2;        // staging row 0..63
    const int sk = (t & 3) * 8;   // staging k-chunk (8 bf16 = 16 B)

    const unsigned short* pB = B_g + (size_t)(col0 + sr) * 800 + sk;
    const unsigned short* pA = A_g + (size_t)(row0 + sr) * 800 + sk;  // t<128 only

    f32x4 acc0 = (f32x4)(0.f), acc1 = (f32x4)(0.f);

    float4 vb = *(const float4*)pB;
    float4 va;
    if (t < 128) va = *(const float4*)pA;

    for (int k0 = 0; k0 < 800; k0 += 32) {
        __syncthreads();
        *(float4*)&Bs[sr][sk] = vb;
        if (t < 128) *(float4*)&As[sr][sk] = va;
        __syncthreads();

        if (k0 + 32 < 800) {  // prefetch next K-tile under compute
            vb = *(const float4*)(pB + k0 + 32);
            if (t < 128) va = *(const float4*)(pA + k0 + 32);
        }

        const bf16x8 a  = *(const bf16x8*)&As[mh * 16 + lm][q * 8];
        const bf16x8 b0 = *(const bf16x8*)&Bs[np * 32 + lm][q * 8];
        const bf16x8 b1v = *(const bf16x8*)&Bs[np * 32 + 16 + lm][q * 8];
        acc0 = __builtin_amdgcn_mfma_f32_16x16x32_bf16(a, b0, acc0, 0, 0, 0);
        acc1 = __builtin_amdgcn_mfma_f32_16x16x32_bf16(a, b1v, acc1, 0, 0, 0);
    }

    const int n0 = col0 + np * 32 + lm;
    const float bias0 = b1[n0];
    const float bias1 = b1[n0 + 16];
#pragma unroll
    for (int i = 0; i < 4; ++i) {
        const int m = row0 + mh * 16 + q * 4 + i;
        H[(size_t)m * 256 + n0]      = fmaxf(acc0[i] + bias0, 0.f);
        H[(size_t)m * 256 + n0 + 16] = fmaxf(acc1[i] + bias1, 0.f);
    }
}

// ---------------------------------------------------------------------------
// Stage 3: logits = H @ W2^T + b2; out = log_softmax(logits).
// One wave per batch row; butterfly shfl reductions.
// ---------------------------------------------------------------------------
__global__ __launch_bounds__(256) void mlp2_lsm_kernel(
        const float* __restrict__ H, const float* __restrict__ W2,
        const float* __restrict__ b2, float* __restrict__ out) {
    const int lane = threadIdx.x & 63;
    const int wv = threadIdx.x >> 6;
    const int b = blockIdx.x * 4 + wv;

    const float4 h = *(const float4*)(H + (size_t)b * 256 + lane * 4);

    float logits[10];
#pragma unroll
    for (int j = 0; j < 10; ++j) {
        const float4 w = *(const float4*)(W2 + (size_t)j * 256 + lane * 4);
        float d = h.x * w.x + h.y * w.y + h.z * w.z + h.w * w.w;
#pragma unroll
        for (int off = 32; off > 0; off >>= 1) d += __shfl_xor(d, off, 64);
        logits[j] = d + b2[j];
    }

    float m = logits[0];
#pragma unroll
    for (int j = 1; j < 10; ++j) m = fmaxf(m, logits[j]);
    float se = 0.f;
#pragma unroll
    for (int j = 0; j < 10; ++j) se += expf(logits[j] - m);
    const float lse = m + logf(se);

    if (lane == 0) {
#pragma unroll
        for (int j = 0; j < 10; ++j) out[(size_t)b * 10 + j] = logits[j] - lse;
    }
}

// ---------------------------------------------------------------------------

extern "C" void kernel_launch(void* const* d_in, const int* in_sizes, int n_in,
                              void* d_out, int out_size, void* d_ws, size_t ws_size,
                              hipStream_t stream) {
    const float* x   = (const float*)d_in[0];  // [B,1,28,28]
    const float* var = (const float*)d_in[1];  // [2,4]
    const float* W1  = (const float*)d_in[2];  // [256,784]
    const float* b1  = (const float*)d_in[3];  // [256]
    const float* W2  = (const float*)d_in[4];  // [10,256]
    const float* b2  = (const float*)d_in[5];  // [10]
    float* out = (float*)d_out;                // [B,10]

    const int B = in_sizes[0] / 784;           // 4096
    const int KP = 800;                        // 784 padded to 25*32

    char* ws = (char*)d_ws;
    unsigned short* fhi  = (unsigned short*)ws;            // [B,800] bf16
    unsigned short* w1hi = fhi + (size_t)B * KP;           // [256,800] bf16
    float* H = (float*)(w1hi + (size_t)256 * KP);          // [B,256] fp32

    const int quanv_total = B * 196;
    const int quanv_blocks = (quanv_total + 255) / 256;    // 3136
    prep_quanv_kernel<<<800 + quanv_blocks, 256, 0, stream>>>(
        x, var, W1, fhi, w1hi, quanv_total);
    gemm1_mfma_kernel<<<dim3(B / 32, 256 / 64), 256, 0, stream>>>(fhi, w1hi, b1, H);
    mlp2_lsm_kernel<<<B / 4, 256, 0, stream>>>(H, W2, b2, out);
}

// Round 5
// 89.713 us; speedup vs baseline: 1.3678x; 1.0900x over previous
//
#include <hip/hip_runtime.h>
#include <math.h>

typedef short bf16x8 __attribute__((ext_vector_type(8)));
typedef float f32x4 __attribute__((ext_vector_type(4)));

#define KP 800        // 784 padded to 25*32
#define AS_LD 808     // LDS A row stride (shorts): 1616 B, 16B-aligned
#define HS_LD 260     // LDS H row stride (floats): 1040 B, 16B-aligned

// ---- fp32 -> bf16 (RNE) ---------------------------------------------------
__device__ __forceinline__ unsigned short f2bf(float f) {
    unsigned int u = __float_as_uint(f);
    u = (u + 0x7FFFu + ((u >> 16) & 1u)) >> 16;
    return (unsigned short)u;
}

// ---------------------------------------------------------------------------
// W1 [256,784] fp32 -> bf16, K-padded to [256,800].
// ---------------------------------------------------------------------------
__global__ __launch_bounds__(256) void w1cvt_kernel(
        const float* __restrict__ W1, unsigned short* __restrict__ w1bf) {
    const int id = blockIdx.x * 256 + threadIdx.x;  // 0 .. 204799
    const int r = id / KP;
    const int c = id - r * KP;
    w1bf[id] = f2bf((c < 784) ? W1[r * 784 + c] : 0.f);
}

// ---------------------------------------------------------------------------
// Fully fused kernel. Block = 512 threads (8 waves), owns 16 batch rows.
// Phase 1: quanv sims (4-qubit real statevector, hw sin/cos) -> bf16 A-tile
//          in LDS. W2/b1/b2 staged to LDS on the side.
//          PAD FIX: all 16 K-pad cols (784..799) zeroed per row — leaving
//          any uninitialized causes NaN*0=NaN in MFMA, then fmaxf flushes
//          to 0 (silent moderate error, R4's 0.4375 absmax).
// Phase 2: barrier-free K-loop: a-frag from LDS, b-frag b128 direct from
//          global bf16 W1 (L2-resident, depth-2 prefetch), 2 MFMA/wave/iter.
// Epilogue: relu+bias H-tile -> LDS; layer2 dot (32 lanes/row) + butterfly
//          shfl reduce + log_softmax; write [16,10] to out.
// ---------------------------------------------------------------------------

__device__ __forceinline__ void ry_gate(float a[16], int bitpos, float c, float s) {
    const int mask = 1 << bitpos;
#pragma unroll
    for (int i = 0; i < 16; ++i) {
        if (!(i & mask)) {
            const int j = i | mask;
            const float a0 = a[i], a1 = a[j];
            a[i] = c * a0 - s * a1;
            a[j] = s * a0 + c * a1;
        }
    }
}

__device__ __forceinline__ void cnot_gate(float a[16], int cbit, int tbit) {
    const int cmask = 1 << cbit, tmask = 1 << tbit;
#pragma unroll
    for (int i = 0; i < 16; ++i) {
        if ((i & cmask) && !(i & tmask)) {
            const int j = i | tmask;
            const float tmp = a[i];
            a[i] = a[j];
            a[j] = tmp;
        }
    }
}

__global__ __launch_bounds__(512) void fused_kernel(
        const float* __restrict__ x, const float* __restrict__ var_angles,
        const unsigned short* __restrict__ w1bf, const float* __restrict__ b1,
        const float* __restrict__ W2, const float* __restrict__ b2,
        float* __restrict__ out) {
    __shared__ unsigned short As[16][AS_LD];   // 25,856 B
    __shared__ float Hs[16][HS_LD];            // 16,640 B
    __shared__ float W2s[2560];                // 10,240 B
    __shared__ float b1s[256];
    __shared__ float b2s[12];

    const int tid = threadIdx.x;
    const int r0 = blockIdx.x * 16;

    // ---- side staging of layer-2 params (overlaps phase 1) ----
#pragma unroll
    for (int i = tid; i < 2560; i += 512) W2s[i] = W2[i];
    if (tid < 256) b1s[tid] = b1[tid];
    if (tid < 10) b2s[tid] = b2[tid];

    // ---- K-pad zeroing: rows 0..15, cols 784..799 (16 shorts per row) ----
    if (tid < 64) {
        const ushort4 zz = {0, 0, 0, 0};
        *(ushort4*)&As[tid >> 2][784 + (tid & 3) * 4] = zz;
    }

    // ---- phase 1: quanv sims into LDS A-tile ----
    float vvc[8], vvs[8];
#pragma unroll
    for (int i = 0; i < 8; ++i) {
        const float h = 0.5f * var_angles[i];
        vvs[i] = __sinf(h);
        vvc[i] = __cosf(h);
    }

    for (int i = tid; i < 16 * 196; i += 512) {
        const int lr = i / 196;
        const int p = i - lr * 196;
        const int pr = p / 14;
        const int pc = p - pr * 14;

        const float* img = x + (size_t)(r0 + lr) * 784;
        const float2 top = *(const float2*)(img + (2 * pr) * 28 + 2 * pc);
        const float2 bot = *(const float2*)(img + (2 * pr + 1) * 28 + 2 * pc);
        const float theta[4] = {top.x, top.y, bot.x, bot.y};

        float c[4], s[4];
#pragma unroll
        for (int w = 0; w < 4; ++w) {
            const float h = 0.5f * theta[w];
            s[w] = __sinf(h);
            c[w] = __cosf(h);
        }

        float a[16];
#pragma unroll
        for (int k = 0; k < 16; ++k) {
            float v = (k & 8) ? s[0] : c[0];
            v *= (k & 4) ? s[1] : c[1];
            v *= (k & 2) ? s[2] : c[2];
            v *= (k & 1) ? s[3] : c[3];
            a[k] = v;
        }

#pragma unroll
        for (int d = 0; d < 2; ++d) {
#pragma unroll
            for (int w = 0; w < 4; ++w)
                ry_gate(a, 3 - w, vvc[d * 4 + w], vvs[d * 4 + w]);
            cnot_gate(a, 3, 2);
            cnot_gate(a, 2, 1);
            cnot_gate(a, 1, 0);
            cnot_gate(a, 0, 3);
        }

        float z[4] = {0.f, 0.f, 0.f, 0.f};
#pragma unroll
        for (int k = 0; k < 16; ++k) {
            const float pr2 = a[k] * a[k];
            z[0] += (k & 8) ? -pr2 : pr2;
            z[1] += (k & 4) ? -pr2 : pr2;
            z[2] += (k & 2) ? -pr2 : pr2;
            z[3] += (k & 1) ? -pr2 : pr2;
        }

        ushort4 hv;
        unsigned short* hp = (unsigned short*)&hv;
#pragma unroll
        for (int w = 0; w < 4; ++w) hp[w] = f2bf(z[w]);
        *(ushort4*)&As[lr][p * 4] = hv;
    }
    __syncthreads();

    // ---- phase 2: barrier-free MFMA K-loop ----
    const int lane = tid & 63;
    const int wv = tid >> 6;      // 8 waves; wave owns cols [wv*32, wv*32+32)
    const int q = lane >> 4;
    const int lm = lane & 15;
    const int n0 = wv * 32;

    const unsigned short* pB0 = w1bf + (size_t)(n0 + lm) * KP + q * 8;
    const unsigned short* pB1 = pB0 + (size_t)16 * KP;

    f32x4 acc0 = (f32x4)(0.f), acc1 = (f32x4)(0.f);

    bf16x8 b0a = *(const bf16x8*)(pB0);
    bf16x8 b1a = *(const bf16x8*)(pB1);
    bf16x8 b0b = *(const bf16x8*)(pB0 + 32);
    bf16x8 b1b = *(const bf16x8*)(pB1 + 32);

    for (int k0 = 0; k0 < KP; k0 += 32) {
        const bf16x8 a = *(const bf16x8*)&As[lm][k0 + q * 8];
        acc0 = __builtin_amdgcn_mfma_f32_16x16x32_bf16(a, b0a, acc0, 0, 0, 0);
        acc1 = __builtin_amdgcn_mfma_f32_16x16x32_bf16(a, b1a, acc1, 0, 0, 0);
        b0a = b0b;
        b1a = b1b;
        if (k0 + 64 < KP) {  // depth-2 prefetch (L2-hit ~200-400 cyc)
            b0b = *(const bf16x8*)(pB0 + k0 + 64);
            b1b = *(const bf16x8*)(pB1 + k0 + 64);
        }
    }

    // ---- epilogue: H-tile (bias+relu) to LDS ----
    const float bias0 = b1s[n0 + lm];
    const float bias1 = b1s[n0 + 16 + lm];
#pragma unroll
    for (int i = 0; i < 4; ++i) {
        const int r = q * 4 + i;  // C/D layout: col=lane&15, row=q*4+reg
        Hs[r][n0 + lm]      = fmaxf(acc0[i] + bias0, 0.f);
        Hs[r][n0 + 16 + lm] = fmaxf(acc1[i] + bias1, 0.f);
    }
    __syncthreads();

    // ---- layer 2 + log_softmax: 32 lanes per row ----
    const int er = tid >> 5;   // row 0..15
    const int el = tid & 31;   // col-group: cols el*8 .. el*8+7

    const float4 h0 = *(const float4*)&Hs[er][el * 8];
    const float4 h1 = *(const float4*)&Hs[er][el * 8 + 4];

    float part[10];
#pragma unroll
    for (int j = 0; j < 10; ++j) {
        const float4 w0 = *(const float4*)&W2s[j * 256 + el * 8];
        const float4 w1 = *(const float4*)&W2s[j * 256 + el * 8 + 4];
        part[j] = h0.x * w0.x + h0.y * w0.y + h0.z * w0.z + h0.w * w0.w +
                  h1.x * w1.x + h1.y * w1.y + h1.z * w1.z + h1.w * w1.w;
    }
#pragma unroll
    for (int mask = 1; mask < 32; mask <<= 1) {
#pragma unroll
        for (int j = 0; j < 10; ++j) part[j] += __shfl_xor(part[j], mask, 64);
    }

    float lg[10];
#pragma unroll
    for (int j = 0; j < 10; ++j) lg[j] = part[j] + b2s[j];
    float m = lg[0];
#pragma unroll
    for (int j = 1; j < 10; ++j) m = fmaxf(m, lg[j]);
    float se = 0.f;
#pragma unroll
    for (int j = 0; j < 10; ++j) se += expf(lg[j] - m);
    const float lse = m + logf(se);

    if (el < 10) out[(size_t)(r0 + er) * 10 + el] = lg[el] - lse;
}

// ---------------------------------------------------------------------------

extern "C" void kernel_launch(void* const* d_in, const int* in_sizes, int n_in,
                              void* d_out, int out_size, void* d_ws, size_t ws_size,
                              hipStream_t stream) {
    const float* x   = (const float*)d_in[0];  // [B,1,28,28]
    const float* var = (const float*)d_in[1];  // [2,4]
    const float* W1  = (const float*)d_in[2];  // [256,784]
    const float* b1  = (const float*)d_in[3];  // [256]
    const float* W2  = (const float*)d_in[4];  // [10,256]
    const float* b2  = (const float*)d_in[5];  // [10]
    float* out = (float*)d_out;                // [B,10]

    const int B = in_sizes[0] / 784;           // 4096

    unsigned short* w1bf = (unsigned short*)d_ws;  // [256,800] bf16

    w1cvt_kernel<<<(256 * KP) / 256, 256, 0, stream>>>(W1, w1bf);
    fused_kernel<<<B / 16, 512, 0, stream>>>(x, var, w1bf, b1, W2, b2, out);
}